// Round 2
// baseline (203.718 us; speedup 1.0000x reference)
//
#include <hip/hip_runtime.h>
#include <hip/hip_bf16.h>

// ContactLoss: Möller–Trumbore parity ray-cast (x2) + nearest-neighbor anchors
// + masked tanh means. All fp32, fp-contract OFF to bit-match numpy reference.
//
// R2: raycast inverted to thread-per-point with LDS-staged triangle chunks
// (register hit accumulation, ~1 atomic/thread/chunk), both passes in one
// dispatch; tri_pre fused; argmins fused; reduce+finalize fused. 5 dispatches.

#define RX 0.4395064455f
#define RY 0.617598629942f
#define RZ 0.652231566745f

// ---------------------------------------------------------------------------
// Precompute per-triangle data for BOTH meshes in one launch:
// {v0.xyz, invdet}, {e1.xyz, flag}, {e2.xyz, 0}, {pvec.xyz, 0}.
// flag = (!parallel) && tri_valid.
// ---------------------------------------------------------------------------
__device__ __forceinline__ void tri_pre_one(const float* __restrict__ vb,
                                            const int* __restrict__ f,
                                            bool split_ok, float4* __restrict__ o) {
#pragma clang fp contract(off)
    int i0 = f[0], i1 = f[1], i2 = f[2];
    float v0x = vb[i0*3+0], v0y = vb[i0*3+1], v0z = vb[i0*3+2];
    float v1x = vb[i1*3+0], v1y = vb[i1*3+1], v1z = vb[i1*3+2];
    float v2x = vb[i2*3+0], v2y = vb[i2*3+1], v2z = vb[i2*3+2];
    float e1x = v1x - v0x, e1y = v1y - v0y, e1z = v1z - v0z;
    float e2x = v2x - v0x, e2y = v2y - v0y, e2z = v2z - v0z;
    float px = RY*e2z - RZ*e2y;
    float py = RZ*e2x - RX*e2z;
    float pz = RX*e2y - RY*e2x;
    float det = (e1x*px + e1y*py) + e1z*pz;       // ((a+b)+c) like np.sum
    float invdet = 1.0f / (det + 1e-8f);          // 0.1*TOL, IEEE div
    bool valid = !(fabsf(det) < 1e-7f) && split_ok;
    o[0] = make_float4(v0x, v0y, v0z, invdet);
    o[1] = make_float4(e1x, e1y, e1z, valid ? 1.0f : 0.0f);
    o[2] = make_float4(e2x, e2y, e2z, 0.0f);
    o[3] = make_float4(px,  py,  pz,  0.0f);
}

__global__ void tri_pre2(const float* __restrict__ hand_verts, const int* __restrict__ hand_faces,
                         const float* __restrict__ obj_verts,  const int* __restrict__ obj_faces,
                         const int* __restrict__ ofsplit,
                         int Nh, int Fh, int No, int Fo, int B,
                         float4* __restrict__ htri, float4* __restrict__ otri) {
    int idx = blockIdx.x * blockDim.x + threadIdx.x;
    int nH = B * Fh;
    if (idx < nH) {
        int b = idx / Fh;
        tri_pre_one(hand_verts + (size_t)b * Nh * 3, hand_faces + (size_t)idx * 3,
                    true, htri + (size_t)idx * 4);
    } else {
        int j = idx - nH;
        if (j >= B * Fo) return;
        int b = j / Fo, t = j - b * Fo;
        tri_pre_one(obj_verts + (size_t)b * No * 3, obj_faces + (size_t)j * 3,
                    t < ofsplit[b], otri + (size_t)j * 4);
    }
}

// ---------------------------------------------------------------------------
// Fused ray cast, both passes. thread = point (coords in VGPRs); triangle
// chunk staged into LDS; inner loop reads LDS (uniform-address broadcast);
// hit count in a register; one atomicAdd per thread per chunk (if nonzero).
// Block decode: flat bid -> {pass, batch, chunk, point-block}.
// ---------------------------------------------------------------------------
#define MAXCHUNK_F4 512   // >= max(chunkA,chunkB)*4

__global__ void raycast2(const float* __restrict__ ptsA, const float4* __restrict__ triA,
                         int PA, int TA, int pbA, int CA, int chunkA, int blocksA,
                         const float* __restrict__ ptsB, const float4* __restrict__ triB,
                         int PB, int TB, int pbB, int CB, int chunkB,
                         const int* __restrict__ ofsplit,
                         int* __restrict__ hitsA, int* __restrict__ hitsB) {
#pragma clang fp contract(off)
    __shared__ float4 s_tri[MAXCHUNK_F4];

    int bid = blockIdx.x;
    const float* pts; const float4* tri; int* hits;
    int P, T, c, pb, b, chunk, tlim;
    if (bid < blocksA) {
        int per_b = pbA * CA;
        b  = bid / per_b;
        int r = bid - b * per_b;
        c  = r / pbA;
        pb = r - c * pbA;
        pts = ptsA; tri = triA; hits = hitsA;
        P = PA; T = TA; chunk = chunkA; tlim = TA;
    } else {
        int j = bid - blocksA;
        int per_b = pbB * CB;
        b  = j / per_b;
        int r = j - b * per_b;
        c  = r / pbB;
        pb = r - c * pbB;
        pts = ptsB; tri = triB; hits = hitsB;
        P = PB; T = TB; chunk = chunkB; tlim = min(TB, ofsplit[b]);
    }

    int tStart = c * chunk;
    if (tStart >= tlim) return;                 // wholly-invalid chunk
    int tEnd = min(tStart + chunk, tlim);
    int nTri = tEnd - tStart;

    const int tid = threadIdx.x;
    // Stage chunk triangles into LDS (coalesced float4 loads).
    const float4* src = tri + ((size_t)b * T + tStart) * 4;
    int n4 = nTri * 4;
    for (int j = tid; j < n4; j += 256) s_tri[j] = src[j];

    // My point.
    int p = pb * 256 + tid;
    float qx = 0.f, qy = 0.f, qz = 0.f;
    if (p < P) {
        const float* q = pts + ((size_t)b * P + p) * 3;
        qx = q[0]; qy = q[1]; qz = q[2];
    }
    __syncthreads();

    int cnt = 0;
    if (p < P) {
        for (int i = 0; i < nTri; ++i) {
            const float4 f0 = s_tri[(i<<2)+0];
            const float4 f1 = s_tri[(i<<2)+1];
            const float4 f2 = s_tri[(i<<2)+2];
            const float4 f3 = s_tri[(i<<2)+3];
            float tvx = qx - f0.x, tvy = qy - f0.y, tvz = qz - f0.z;
            float u  = ((tvx*f3.x + tvy*f3.y) + tvz*f3.z) * f0.w;
            float qvx = tvy*f1.z - tvz*f1.y;
            float qvy = tvz*f1.x - tvx*f1.z;
            float qvz = tvx*f1.y - tvy*f1.x;
            float v  = ((qvx*RX + qvy*RY) + qvz*RZ) * f0.w;
            float tt = ((f2.x*qvx + f2.y*qvy) + f2.z*qvz) * f0.w;
            bool hit = (u > 0.0f) && (u < 1.0f) && (v > 0.0f) &&
                       ((u + v) < 1.0f) && (tt > 1e-7f) && (f1.w != 0.0f);
            cnt += hit ? 1 : 0;
        }
        if (cnt) atomicAdd(&hits[(size_t)b * P + p], cnt);
    }
}

// ---------------------------------------------------------------------------
// Fused argmins: wave w < B*Nh -> hand vertex vs valid obj verts;
// else -> (valid) obj vertex vs all hand verts. Packed (dist<<32)|idx min
// => first-occurrence tie-break like np.argmin.
// ---------------------------------------------------------------------------
__global__ void min_fused(const float* __restrict__ hand_verts,
                          const float* __restrict__ obj_verts,
                          const int* __restrict__ ovsplit,
                          int Nh, int No, int B,
                          float* __restrict__ anchor_h, float* __restrict__ anchor_o) {
#pragma clang fp contract(off)
    int w = (blockIdx.x * blockDim.x + threadIdx.x) >> 6;
    int lane = threadIdx.x & 63;
    int nHand = B * Nh;
    const float* refv; const float* loopv; int loopN; float* outp;
    int b;
    if (w < nHand) {
        b = w / Nh;
        int n = w - b * Nh;
        refv  = hand_verts + ((size_t)b * Nh + n) * 3;
        loopv = obj_verts + (size_t)b * No * 3;
        loopN = ovsplit[b];
        outp  = anchor_h + (size_t)b * Nh + n;
    } else {
        int j = w - nHand;
        if (j >= B * No) return;
        b = j / No;
        int m = j - b * No;
        if (m >= ovsplit[b]) return;
        refv  = obj_verts + ((size_t)b * No + m) * 3;
        loopv = hand_verts + (size_t)b * Nh * 3;
        loopN = Nh;
        outp  = anchor_o + (size_t)b * No + m;
    }
    float hx = refv[0], hy = refv[1], hz = refv[2];
    float rx = (hx*hx + hy*hy) + hz*hz;
    unsigned long long best = ~0ull;
    for (int m = lane; m < loopN; m += 64) {
        float ox = loopv[m*3+0], oy = loopv[m*3+1], oz = loopv[m*3+2];
        float ry = (ox*ox + oy*oy) + oz*oz;
        float zz = (hx*ox + hy*oy) + hz*oz;
        float d = (rx + ry) - 2.0f * zz;
        unsigned long long e = ((unsigned long long)__float_as_uint(d) << 32) | (unsigned)m;
        if (e < best) best = e;
    }
    for (int off = 32; off > 0; off >>= 1) {
        unsigned long long o = __shfl_xor(best, off, 64);
        if (o < best) best = o;
    }
    if (lane == 0) {
        int idx = (best == ~0ull) ? 0 : (int)(best & 0xffffffffu);
        const float* cv = loopv + (size_t)idx * 3;
        float dx = cv[0] - hx, dy = cv[1] - hy, dz = cv[2] - hz;
        *outp = sqrtf((dx*dx + dy*dy) + dz*dz);
    }
}

// ---------------------------------------------------------------------------
// Single-launch reduce: one block, wave w handles batches w, w+4, ...
// Row losses written directly; global losses from LDS partials by thread 0.
// out = [missed_loss, penetr_loss, missed_losses[B], penetr_losses[B]].
// ---------------------------------------------------------------------------
__global__ void reduce_all(const int* __restrict__ hits_hand, const int* __restrict__ hits_obj,
                           const float* __restrict__ anchor_h, const float* __restrict__ anchor_o,
                           const int* __restrict__ ovsplit, int Nh, int No, int B,
                           float* __restrict__ out) {
    __shared__ float part[64][6];
    int tid = threadIdx.x, wave = tid >> 6, lane = tid & 63;
    for (int b = wave; b < B; b += 4) {
        float s0=0.f,s1=0.f,s2=0.f,s3=0.f,s4=0.f,s5=0.f;
        for (int n = lane; n < Nh; n += 64) {
            bool ext = (hits_hand[(size_t)b*Nh + n] & 1) == 0;
            float val = 25.0f * tanhf(anchor_h[(size_t)b*Nh + n] / 25.0f);
            if (ext) { s0 += val; s1 += 1.0f; } else { s2 += val; s3 += 1.0f; }
        }
        int split = ovsplit[b];
        for (int m = lane; m < split; m += 64) {
            if ((hits_obj[(size_t)b*No + m] & 1) != 0) {   // interior & valid
                s4 += 25.0f * tanhf(anchor_o[(size_t)b*No + m] / 25.0f);
                s5 += 1.0f;
            }
        }
        for (int off = 32; off > 0; off >>= 1) {
            s0 += __shfl_xor(s0, off, 64);
            s1 += __shfl_xor(s1, off, 64);
            s2 += __shfl_xor(s2, off, 64);
            s3 += __shfl_xor(s3, off, 64);
            s4 += __shfl_xor(s4, off, 64);
            s5 += __shfl_xor(s5, off, 64);
        }
        if (lane == 0) {
            out[2 + b]  = (s1 > 0.f) ? s0 / fmaxf(s1, 1.f) : 0.f;
            float ph    = (s3 > 0.f) ? s2 / fmaxf(s3, 1.f) : 0.f;
            float po    = (s5 > 0.f) ? s4 / fmaxf(s5, 1.f) : 0.f;
            out[10 + b] = ph + po;
            part[b][0]=s0; part[b][1]=s1; part[b][2]=s2;
            part[b][3]=s3; part[b][4]=s4; part[b][5]=s5;
        }
    }
    __syncthreads();
    if (tid == 0) {
        float sm=0.f,cm=0.f,sph=0.f,cph=0.f,spo=0.f,cpo=0.f;
        for (int b = 0; b < B; ++b) {
            sm  += part[b][0]; cm  += part[b][1]; sph += part[b][2];
            cph += part[b][3]; spo += part[b][4]; cpo += part[b][5];
        }
        float missed = (cm  > 0.f) ? sm  / fmaxf(cm , 1.f) : 0.f;
        float ph     = (cph > 0.f) ? sph / fmaxf(cph, 1.f) : 0.f;
        float po     = (cpo > 0.f) ? spo / fmaxf(cpo, 1.f) : 0.f;
        out[0] = missed;
        out[1] = ph + po;
    }
}

// ---------------------------------------------------------------------------
extern "C" void kernel_launch(void* const* d_in, const int* in_sizes, int n_in,
                              void* d_out, int out_size, void* d_ws, size_t ws_size,
                              hipStream_t stream) {
    const float* hand_verts = (const float*)d_in[0];
    const int*   hand_faces = (const int*)d_in[1];
    const float* obj_verts  = (const float*)d_in[2];
    const int*   obj_faces  = (const int*)d_in[3];
    const int*   ovsplit    = (const int*)d_in[4];
    const int*   ofsplit    = (const int*)d_in[5];
    float* out = (float*)d_out;

    const int B  = in_sizes[4];
    const int Nh = in_sizes[0] / (3 * B);
    const int Fh = in_sizes[1] / (3 * B);
    const int No = in_sizes[2] / (3 * B);
    const int Fo = in_sizes[3] / (3 * B);

    char* ws = (char*)d_ws;
    size_t off = 0;
    auto alloc = [&](size_t bytes) -> void* {
        void* p = ws + off;
        off = (off + bytes + 255) & ~(size_t)255;
        return p;
    };
    float4* htri      = (float4*)alloc((size_t)B * Fh * 4 * sizeof(float4));
    float4* otri      = (float4*)alloc((size_t)B * Fo * 4 * sizeof(float4));
    int*    hits      = (int*)   alloc((size_t)B * (No + Nh) * sizeof(int));
    int*    hits_obj  = hits;                    // [B*No]
    int*    hits_hand = hits + (size_t)B * No;   // [B*Nh]
    float*  anchor_h  = (float*) alloc((size_t)B * Nh * sizeof(float));
    float*  anchor_o  = (float*) alloc((size_t)B * No * sizeof(float));

    hipMemsetAsync(hits, 0, (size_t)B * (No + Nh) * sizeof(int), stream);

    // 1. Fused triangle precompute.
    int totT = B * (Fh + Fo);
    tri_pre2<<<(totT + 255) / 256, 256, 0, stream>>>(hand_verts, hand_faces,
                                                     obj_verts, obj_faces, ofsplit,
                                                     Nh, Fh, No, Fo, B, htri, otri);

    // 2. Fused ray cast (both passes, one dispatch).
    const int CA = 16, CB = 32;                       // triangle chunks per pass
    int chunkA = (Fh + CA - 1) / CA;                  // 97  for Fh=1538
    int chunkB = (Fo + CB - 1) / CB;                  // 125 for Fo=4000
    int pbA = (No + 255) / 256, pbB = (Nh + 255) / 256;
    int blocksA = pbA * CA * B, blocksB = pbB * CB * B;
    raycast2<<<blocksA + blocksB, 256, 0, stream>>>(
        obj_verts,  htri, No, Fh, pbA, CA, chunkA, blocksA,
        hand_verts, otri, Nh, Fo, pbB, CB, chunkB, ofsplit,
        hits_obj, hits_hand);

    // 3. Fused argmins.
    int waves = B * (Nh + No);
    min_fused<<<(waves * 64 + 255) / 256, 256, 0, stream>>>(hand_verts, obj_verts, ovsplit,
                                                            Nh, No, B, anchor_h, anchor_o);

    // 4. Single-block reduce (row + global losses).
    reduce_all<<<1, 256, 0, stream>>>(hits_hand, hits_obj, anchor_h, anchor_o,
                                      ovsplit, Nh, No, B, out);
}